// Round 18
// baseline (119.050 us; speedup 1.0000x reference)
//
#include <hip/hip_runtime.h>
#include <hip/hip_bf16.h>
#include <stdint.h>

typedef short bf16x8 __attribute__((ext_vector_type(8)));
typedef float f32x4 __attribute__((ext_vector_type(4)));

#define T_M   512
#define ML_   1536
#define LSEQ  1568
#define NHEAD 12
#define DHEAD 64
#define CDIM  768
#define NSEG  8
#define MROWS 6272  // B*L
#define CQK   1536  // q|k concat row stride
#define VTN   6272  // vt row length
#define NX4   1204224  // MROWS*CDIM/4
#define NW4   147456   // CDIM*CDIM/4
#define NWE   589824   // CDIM*CDIM
#define SCALE2 0.1803368801111244f  // 0.125 * log2(e)
#define SLOTF 4224  // floats per split slot: O[64][64] + m[64] + l[64]

__device__ __forceinline__ unsigned short f2bf(float f) {
  __hip_bfloat16 h = __float2bfloat16(f);
  return *reinterpret_cast<unsigned short*>(&h);
}

__device__ __forceinline__ void gll16(const void* g, void* l) {
  auto* lp = reinterpret_cast<__attribute__((address_space(3))) unsigned int*>(
      reinterpret_cast<uintptr_t>(l));
  auto* gp = reinterpret_cast<const __attribute__((address_space(1))) unsigned int*>(
      reinterpret_cast<uintptr_t>(g));
  __builtin_amdgcn_global_load_lds(gp, lp, 16, 0, 0);
}

__device__ __forceinline__ f32x4 mfma16(bf16x8 a, bf16x8 b, f32x4 c) {
  return __builtin_amdgcn_mfma_f32_16x16x32_bf16(a, b, c, 0, 0, 0);
}

// Bijective XCD-chunk remap (m204): consecutive wgids land on one XCD.
__device__ __forceinline__ int xcd_chunk(int orig, int nwg) {
  int q = nwg >> 3, r = nwg & 7;
  int xcd = orig & 7, i = orig >> 3;
  return (xcd < r ? xcd * (q + 1) : r * (q + 1) + (xcd - r) * q) + i;
}

// Single fused f32->bf16 convert for x, Wq, Wk, Wv, Wp.
__global__ __launch_bounds__(256) void cvt5_kernel(const float* __restrict__ x,
                                                   const float* __restrict__ wq,
                                                   const float* __restrict__ wk,
                                                   const float* __restrict__ wv,
                                                   const float* __restrict__ wp,
                                                   unsigned short* __restrict__ xb,
                                                   unsigned short* __restrict__ wqkb,
                                                   unsigned short* __restrict__ wvb,
                                                   unsigned short* __restrict__ wpb) {
  int gid = blockIdx.x * 256 + threadIdx.x;
  const float* src;
  unsigned short* dst;
  int idx;
  if (gid < NX4) {
    src = x; dst = xb; idx = gid;
  } else {
    int g = gid - NX4;
    int region = g / NW4;
    idx = g - region * NW4;
    if (region == 0)      { src = wq; dst = wqkb; }
    else if (region == 1) { src = wk; dst = wqkb + NWE; }
    else if (region == 2) { src = wv; dst = wvb; }
    else                  { src = wp; dst = wpb; }
  }
  float4 v = reinterpret_cast<const float4*>(src)[idx];
  __hip_bfloat162 lo = __float22bfloat162_rn({v.x, v.y});
  __hip_bfloat162 hi = __float22bfloat162_rn({v.z, v.w});
  uint2 st;
  st.x = *reinterpret_cast<unsigned*>(&lo);
  st.y = *reinterpret_cast<unsigned*>(&hi);
  reinterpret_cast<uint2*>(dst)[idx] = st;
}

// Shared GEMM body (128x128, 256 thr): C[m,n] = (sum A[m,k]*Bw[n,k] + bias)*sc.
template <int OUT_BF16, int BIAS_ROW>
__device__ __forceinline__ void gemm_body(char* smem, int bx, int by,
                                          const unsigned short* __restrict__ A,
                                          const unsigned short* __restrict__ Bw,
                                          const float* __restrict__ bias0,
                                          const float* __restrict__ bias1, int bsplit,
                                          float sc0, float sc1,
                                          void* __restrict__ Cout,
                                          int M, int N, int K) {
  const int tid = threadIdx.x;
  const int lane = tid & 63;
  const int w = tid >> 6;
  const int m0 = by * 128, n0 = bx * 128;
  const int wr = (w >> 1) * 64, wc = (w & 1) * 64;

  unsigned gaoff[4], gboff[4];
#pragma unroll
  for (int it = 0; it < 4; ++it) {
    int off = it * 4096 + tid * 16;
    int r = off >> 7;
    int cb = (off & 127) ^ ((r & 7) << 4);
    gaoff[it] = (unsigned)((m0 + r) * K * 2 + cb);
    gboff[it] = (unsigned)((n0 + r) * K * 2 + cb);
  }
  const char* Ab = (const char*)A;
  const char* Bb = (const char*)Bw;

  f32x4 acc[4][4] = {};

  for (int ks = 0; ks < K; ks += 64) {
    __syncthreads();
#pragma unroll
    for (int it = 0; it < 4; ++it) {
      gll16(Ab + gaoff[it] + ks * 2, smem + it * 4096 + tid * 16);
      gll16(Bb + gboff[it] + ks * 2, smem + 16384 + it * 4096 + tid * 16);
    }
    __syncthreads();
#pragma unroll
    for (int kk = 0; kk < 2; ++kk) {
      const int cb = kk * 64 + (lane >> 4) * 16;
      bf16x8 av[4], bv[4];
#pragma unroll
      for (int mi = 0; mi < 4; ++mi) {
        int r = wr + mi * 16 + (lane & 15);
        av[mi] = *reinterpret_cast<const bf16x8*>(smem + r * 128 + (cb ^ ((r & 7) << 4)));
      }
#pragma unroll
      for (int ni = 0; ni < 4; ++ni) {
        int r = wc + ni * 16 + (lane & 15);
        bv[ni] = *reinterpret_cast<const bf16x8*>(smem + 16384 + r * 128 + (cb ^ ((r & 7) << 4)));
      }
#pragma unroll
      for (int mi = 0; mi < 4; ++mi)
#pragma unroll
        for (int ni = 0; ni < 4; ++ni)
          acc[mi][ni] = mfma16(av[mi], bv[ni], acc[mi][ni]);
    }
  }

#pragma unroll
  for (int mi = 0; mi < 4; ++mi) {
#pragma unroll
    for (int ni = 0; ni < 4; ++ni) {
      int col = n0 + wc + ni * 16 + (lane & 15);
      float bsc = BIAS_ROW ? 0.f : (col < bsplit ? bias0[col] : bias1[col - bsplit]);
      float scc = BIAS_ROW ? 1.f : (col < bsplit ? sc0 : sc1);
#pragma unroll
      for (int reg = 0; reg < 4; ++reg) {
        int row = m0 + wr + mi * 16 + (lane >> 4) * 4 + reg;
        float v = (acc[mi][ni][reg] + (BIAS_ROW ? bias0[row] : bsc)) * scc;
        if (OUT_BF16)
          ((unsigned short*)Cout)[(size_t)row * N + col] = f2bf(v);
        else
          ((float*)Cout)[(size_t)row * N + col] = v;
      }
    }
  }
}

// Fused pre-attention GEMMs with XCD-chunked block remap.
__global__ __launch_bounds__(256) void gemm_pre(const unsigned short* __restrict__ xb,
                                                const unsigned short* __restrict__ wqkb,
                                                const unsigned short* __restrict__ wvb,
                                                const float* __restrict__ bq,
                                                const float* __restrict__ bk,
                                                const float* __restrict__ bv,
                                                unsigned short* __restrict__ qkbuf,
                                                unsigned short* __restrict__ vtbuf) {
  __shared__ char smem[32768];
  int bid = xcd_chunk(blockIdx.x, 882);
  if (bid < 588) {
    gemm_body<1, 0>(smem, bid % 12, bid / 12, xb, wqkb, bq, bk, 768, SCALE2, 1.0f,
                    qkbuf, MROWS, CQK, CDIM);
  } else {
    int b2 = bid - 588;
    gemm_body<1, 1>(smem, b2 % 49, b2 / 49, wvb, xb, bv, bv, 0, 1.0f, 1.0f,
                    vtbuf, CDIM, MROWS, CDIM);
  }
}

// Final projection GEMM, 1-D grid + XCD-chunked remap.
__global__ __launch_bounds__(256) void gemm_post(const unsigned short* __restrict__ ybuf,
                                                 const unsigned short* __restrict__ wpb,
                                                 const float* __restrict__ bp,
                                                 float* __restrict__ out) {
  __shared__ char smem[32768];
  int bid = xcd_chunk(blockIdx.x, 294);
  gemm_body<0, 0>(smem, bid % 6, bid / 6, ybuf, wpb, bp, bp, 1 << 30, 1.0f, 1.0f,
                  out, MROWS, CDIM, CDIM);
}

// 32 y-entries: heavy qt (niter>=10: 13,14,15,21,22,23,24) split into 2 pieces
// (pc=1 first half, pc=2 second half); rest unsplit (pc=0). LPT-ordered by
// piece length (max chain 8 = qt12/20).
__device__ const unsigned char ytab_qt[32] = {
    12, 20, 11, 19, 15, 23, 24, 14, 22, 15, 23, 24, 10, 18, 13, 13,
    21, 21, 14, 22, 6, 7, 9, 17, 4, 5, 2, 3, 8, 16, 0, 1};
__device__ const unsigned char ytab_pc[32] = {
    0, 0, 0, 0, 1, 1, 1, 1, 1, 2, 2, 2, 0, 0, 1, 2,
    1, 2, 2, 2, 0, 0, 0, 0, 0, 0, 0, 0, 0, 0, 0, 0};

// next included KV-tile after kt for this qt
__device__ __forceinline__ int step_kt(int kt, int rb, int qtl) {
  if (rb == 0 || rb == 3) return kt + 1;
  if ((kt & 7) < qtl) return kt + 1;
  if (kt < 16) return (kt & ~7) + 8;
  return 24;
}

// Flash attention (R17 body, proven 51.2us) + heavy-qt 2-way block split:
// split pieces write unnormalized (M,L,O) to workspace (dead xb region);
// merge2 kernel combines. Grid: (48 bh, 32 entries), 512 threads.
__global__ __launch_bounds__(512) void attn_kernel(const unsigned short* __restrict__ qk,
                                                   const unsigned short* __restrict__ vt,
                                                   unsigned short* __restrict__ yb,
                                                   float* __restrict__ wsp,
                                                   const int* __restrict__ seg_s,
                                                   const int* __restrict__ seg_e) {
  __shared__ char smem[49664];  // [2 tiles][K 8KB|V 8KB] + P[8][2KB] + m/l 512B
  const int tid = threadIdx.x;
  const int lane = tid & 63;
  const int w = tid >> 6;
  const int lh = lane & 15, lg = lane >> 4;
  const int bh = blockIdx.x;
  const int b = bh / NHEAD, h = bh % NHEAD;
  const int qt = ytab_qt[blockIdx.y];
  const int pc = ytab_pc[blockIdx.y];
  const int wsub = w & 3;
  const int half = w >> 2;
  const int rb_q = qt >> 3;   // 0,1,2 motion; 3 text
  const int qtl = qt & 7;
  const int cnt = (rb_q == 0) ? (qtl + 1) : (rb_q < 3 ? 3 * (qtl + 1) + 1 : 25);
  char* pw = smem + 32768 + w * 2048;

  // Q fragments (pre-scaled into log2 domain); MFMA B-operand.
  int qr = qt * 64 + wsub * 16 + lh;
  if (qr >= LSEQ) qr = LSEQ - 1;
  const unsigned short* qp = qk + ((size_t)(b * LSEQ + qr) * CQK + h * DHEAD + lg * 8);
  const bf16x8 qf0 = *reinterpret_cast<const bf16x8*>(qp);
  const bf16x8 qf1 = *reinterpret_cast<const bf16x8*>(qp + 32);

  const char* qkc = (const char*)qk + (size_t)b * LSEQ * CQK * 2;
  const char* vtc = (const char*)vt + (size_t)b * LSEQ * 2;

  // staging precompute (waves 0-3: K rows, waves 4-7: V rows). Affine in kt.
  const int cbyte = (((lane & 7) ^ (lane >> 3)) << 4);
  const int rlA = (w & 3) * 16 + (lane >> 3);
  const char* kqbase = qkc + (768 + h * DHEAD) * 2 + cbyte;
  const char* kAbase[2];
#pragma unroll
  for (int t = 0; t < 2; ++t)
    kAbase[t] = kqbase + (size_t)(rlA + t * 8) * (CQK * 2);
  const char* vAbase[2];
#pragma unroll
  for (int t = 0; t < 2; ++t)
    vAbase[t] = vtc + (size_t)(h * DHEAD + rlA + t * 8) * (VTN * 2) + cbyte;

  const int c0 = (lg * 16) ^ ((lh & 7) << 4);

  // loop-invariant mask data (swapped layout: lane q = lh; k = nt*16+lg*4+reg)
  const int f_lane = (qt * 64 + wsub * 16 + lh) & 511;
  float a_k[4];
#pragma unroll
  for (int nt = 0; nt < 4; ++nt) {
    int j = nt * 2 + (lg >> 1);
    bool st = (rb_q == 3) || ((rb_q == 1) ? (j != 1) : (j != 0));
    a_k[nt] = (nt < 2 && st) ? 0.f : -1e30f;
  }
  float w4[4];
#pragma unroll
  for (int reg = 0; reg < 4; ++reg) {
    int ii = (lg * 4 + reg) & 7;
    int ssv = seg_s[b * NSEG + ii], sev = seg_e[b * NSEG + ii];
    w4[reg] = (rb_q == 3) ? 0.f : ((f_lane >= ssv && f_lane < sev) ? 0.f : -1e30f);
  }

  // P LDS addresses
  int pfa[2];
#pragma unroll
  for (int jc = 0; jc < 2; ++jc)
    pfa[jc] = lh * 128 + (((jc * 32 + lg * 8) * 2) ^ ((lh & 7) << 4));
  int pwr[4];
#pragma unroll
  for (int nt = 0; nt < 4; ++nt)
    pwr[nt] = lh * 128 + ((nt * 32 + lg * 8) ^ ((lh & 7) << 4));

  const short oneb = (short)0x3F80;
  const bf16x8 ones = {oneb, oneb, oneb, oneb, oneb, oneb, oneb, oneb};

  f32x4 o[4] = {};
  f32x4 l_acc = {};
  float m_run = -1e30f;  // per-lane (q = lh), log2 domain

  int ktA = 0;
  int ktB = step_kt(0, rb_q, qtl);
  if (ktB > 24) ktB = 24;
  const int niter = (cnt + 1) >> 1;

  int j0 = 0, jend = niter;
  if (pc) {
    int hh = (niter + 1) >> 1;
    if (pc == 1) {
      jend = hh;
    } else {
      j0 = hh;
      for (int i = 0; i < hh; ++i) {
        ktA = step_kt(ktB, rb_q, qtl);
        if (ktA > 24) ktA = 24;
        ktB = step_kt(ktA, rb_q, qtl);
        if (ktB > 24) ktB = 24;
      }
    }
  }

  for (int j = j0; j < jend; ++j) {
    __syncthreads();  // previous pair fully consumed

    // stage both halves' tiles (single-buffered, affine addresses)
    int kts0 = ktA, kts1 = ktB;
#pragma unroll
    for (int q = 0; q < 2; ++q) {
      int kt = q ? kts1 : kts0;
#pragma unroll
      for (int t = 0; t < 2; ++t) {
        char* dst = smem + q * 16384 + (w < 4 ? 0 : 8192) + (2 * (w & 3) + t) * 1024 +
                    lane * 16;
        const char* src = (w < 4) ? (kAbase[t] + (size_t)kt * (64 * CQK * 2))
                                  : (vAbase[t] + (size_t)kt * 128);
        gll16(src, dst);
      }
    }
    __syncthreads();  // staged (compiler drains vmcnt)

    const int myidx = 2 * j + half;
    if (myidx < cnt) {
      const int kt = half ? ktB : ktA;
      const bool kt24 = (kt == 24);  // wave-uniform
      const char* kb = smem + half * 16384;
      const char* vb = kb + 8192;

      // S^T = K Q^T : s[nt][reg] = S[q=lh][k = nt*16 + lg*4 + reg]
      f32x4 s[4];
#pragma unroll
      for (int nt = 0; nt < 4; ++nt) {
        if (nt >= 2 && kt24) {
          s[nt][0] = s[nt][1] = s[nt][2] = s[nt][3] = -1e30f;
        } else {
          const char* kr = kb + (nt * 16 + lh) * 128;
          bf16x8 k0 = *reinterpret_cast<const bf16x8*>(kr + c0);
          bf16x8 k1 = *reinterpret_cast<const bf16x8*>(kr + (c0 ^ 64));
          f32x4 z = {};
          z = mfma16(k0, qf0, z);
          z = mfma16(k1, qf1, z);
          s[nt] = z;
        }
      }

      // mask
      if (kt24) {
#pragma unroll
        for (int nt = 0; nt < 2; ++nt)
#pragma unroll
          for (int reg = 0; reg < 4; ++reg)
            s[nt][reg] += a_k[nt] + w4[reg];
      } else if (rb_q < 3 && (kt & 7) == qtl) {
        const int cbk = kt >> 3;
        const bool strict = (rb_q == 1) ? (cbk != 0) : ((rb_q == 2) ? (cbk == 2) : false);
        const int dbase = qtl * 64 + lg * 4;
#pragma unroll
        for (int nt = 0; nt < 4; ++nt)
#pragma unroll
          for (int reg = 0; reg < 4; ++reg) {
            int kcol = dbase + nt * 16 + reg;
            bool ok = strict ? (kcol < f_lane) : (kcol <= f_lane);
            s[nt][reg] = ok ? s[nt][reg] : -1e30f;
          }
      }

      // lane-local row max + 2 cross-lg shfl steps
      float mt = s[0][0];
#pragma unroll
      for (int nt = 0; nt < 4; ++nt)
#pragma unroll
        for (int reg = 0; reg < 4; ++reg)
          if (nt || reg) mt = fmaxf(mt, s[nt][reg]);
      mt = fmaxf(mt, __shfl_xor(mt, 16));
      mt = fmaxf(mt, __shfl_xor(mt, 32));

      if (!__all(mt <= -1e29f)) {
        if (!__all(mt <= m_run + 12.f)) {
          float mold = m_run;
          m_run = fmaxf(m_run, mt);
          float fc = exp2f(mold - m_run);
          float fcC[4];
#pragma unroll
          for (int reg = 0; reg < 4; ++reg) fcC[reg] = __shfl(fc, lg * 4 + reg);
#pragma unroll
          for (int reg = 0; reg < 4; ++reg) {
            l_acc[reg] *= fcC[reg];
#pragma unroll
            for (int dt = 0; dt < 4; ++dt) o[dt][reg] *= fcC[reg];
          }
        }

        // exp + packed P write (4 x ds_write_b64); kt==24 upper half is zero
#pragma unroll
        for (int nt = 0; nt < 4; ++nt) {
          uint2 pk;
          if (nt >= 2 && kt24) {
            pk.x = 0u; pk.y = 0u;
          } else {
            float p0 = exp2f(s[nt][0] - m_run);
            float p1 = exp2f(s[nt][1] - m_run);
            float p2 = exp2f(s[nt][2] - m_run);
            float p3 = exp2f(s[nt][3] - m_run);
            __hip_bfloat162 lo = __float22bfloat162_rn({p0, p1});
            __hip_bfloat162 hi = __float22bfloat162_rn({p2, p3});
            pk.x = *reinterpret_cast<unsigned*>(&lo);
            pk.y = *reinterpret_cast<unsigned*>(&hi);
          }
          *reinterpret_cast<uint2*>(pw + pwr[nt]) = pk;
        }

        // O += P @ V ; l += P @ 1   (kt==24: jc=1 spans k 32..63, all-zero P)
#pragma unroll
        for (int jc = 0; jc < 2; ++jc) {
          if (jc == 0 || !kt24) {
            bf16x8 pf = *reinterpret_cast<const bf16x8*>(pw + pfa[jc]);
#pragma unroll
            for (int dt = 0; dt < 4; ++dt) {
              bf16x8 vf = *reinterpret_cast<const bf16x8*>(
                  vb + (dt * 16 + lh) * 128 + (c0 ^ (jc << 6)));
              o[dt] = mfma16(pf, vf, o[dt]);
            }
            l_acc = mfma16(pf, ones, l_acc);
          }
        }
      }
    }

    // advance both halves' tiles by 2 positions
    ktA = step_kt(ktB, rb_q, qtl);
    if (ktA > 24) ktA = 24;
    ktB = step_kt(ktA, rb_q, qtl);
    if (ktB > 24) ktB = 24;
  }

  // ---- merge the two KV-halves (reuse staging LDS) ----
  float* olds = (float*)smem;                 // [4][16][64] f32 = 16KB
  float* mf = (float*)(smem + 16384);         // [4][16]
  float* lf = (float*)(smem + 16384 + 256);   // [4][16]
  __syncthreads();
  if (half == 0) {
#pragma unroll
    for (int reg = 0; reg < 4; ++reg) {
#pragma unroll
      for (int dt = 0; dt < 4; ++dt)
        olds[(wsub * 16 + lg * 4 + reg) * 64 + dt * 16 + lh] = o[dt][reg];
      if (lh == 0) lf[wsub * 16 + lg * 4 + reg] = l_acc[reg];
    }
    if (lg == 0) mf[wsub * 16 + lh] = m_run;
  }
  __syncthreads();
  if (half == 1) {
    if (pc == 0) {
#pragma unroll
      for (int reg = 0; reg < 4; ++reg) {
        int row = lg * 4 + reg;
        int r = qt * 64 + wsub * 16 + row;
        if (r >= LSEQ) continue;
        float m1 = mf[wsub * 16 + row];
        float l1 = lf[wsub * 16 + row];
        float m2 = __shfl(m_run, row);
        float M = fmaxf(m1, m2);
        float w1 = exp2f(m1 - M);
        float w2 = exp2f(m2 - M);
        float inv = 1.0f / (l1 * w1 + l_acc[reg] * w2);
#pragma unroll
        for (int dt = 0; dt < 4; ++dt) {
          int col = dt * 16 + lh;
          float v = (olds[(wsub * 16 + row) * 64 + col] * w1 + o[dt][reg] * w2) * inv;
          yb[(size_t)(b * LSEQ + r) * CDIM + h * DHEAD + col] = f2bf(v);
        }
      }
    } else {
      // split piece: write unnormalized merged (M, L, O) to workspace slot
      int sidx = (qt < 16 ? qt - 13 : qt - 18);
      float* slot = wsp + (size_t)(sidx * 96 + bh * 2 + (pc - 1)) * SLOTF;
#pragma unroll
      for (int reg = 0; reg < 4; ++reg) {
        int row = lg * 4 + reg;
        int grow = wsub * 16 + row;
        float m1 = mf[grow];
        float l1 = lf[grow];
        float m2 = __shfl(m_run, row);
        float M = fmaxf(m1, m2);
        float w1 = exp2f(m1 - M);
        float w2 = exp2f(m2 - M);
        float L = l1 * w1 + l_acc[reg] * w2;
#pragma unroll
        for (int dt = 0; dt < 4; ++dt) {
          int col = dt * 16 + lh;
          slot[grow * 64 + col] = olds[grow * 64 + col] * w1 + o[dt][reg] * w2;
        }
        if (lh == 0) {
          slot[4096 + grow] = M;
          slot[4160 + grow] = L;
        }
      }
    }
  }
}

// Merge the two pieces of each split (qt, bh) into y.
__global__ __launch_bounds__(256) void merge2(const float* __restrict__ wsp,
                                              unsigned short* __restrict__ yb) {
  const int u = blockIdx.x;            // 0..335
  const int si = u / 48, bh = u % 48;
  const int qt = (si < 3) ? (13 + si) : (18 + si);  // {13,14,15,21,22,23,24}
  const int b = bh / NHEAD, hd = bh % NHEAD;
  const float* s0 = wsp + (size_t)(si * 96 + bh * 2 + 0) * SLOTF;
  const float* s1 = wsp + (size_t)(si * 96 + bh * 2 + 1) * SLOTF;
  const int rr = threadIdx.x >> 2;
  const int c0 = (threadIdx.x & 3) * 16;
  const int r = qt * 64 + rr;
  if (r >= LSEQ) return;
  float m0v = s0[4096 + rr], l0v = s0[4160 + rr];
  float m1v = s1[4096 + rr], l1v = s1[4160 + rr];
  float M = fmaxf(m0v, m1v);
  float wA = exp2f(m0v - M), wB = exp2f(m1v - M);
  float inv = 1.0f / (l0v * wA + l1v * wB);
  unsigned short* dst = yb + (size_t)(b * LSEQ + r) * CDIM + hd * DHEAD + c0;
#pragma unroll
  for (int i = 0; i < 16; ++i) {
    float v = (s0[rr * 64 + c0 + i] * wA + s1[rr * 64 + c0 + i] * wB) * inv;
    dst[i] = f2bf(v);
  }
}

extern "C" void kernel_launch(void* const* d_in, const int* in_sizes, int n_in,
                              void* d_out, int out_size, void* d_ws, size_t ws_size,
                              hipStream_t stream) {
  (void)in_sizes; (void)n_in; (void)out_size;
  const float* x  = (const float*)d_in[0];
  const float* Wq = (const float*)d_in[1];
  const float* bq = (const float*)d_in[2];
  const float* Wk = (const float*)d_in[3];
  const float* bk = (const float*)d_in[4];
  const float* Wv = (const float*)d_in[5];
  const float* bv = (const float*)d_in[6];
  const float* Wp = (const float*)d_in[7];
  const float* bp = (const float*)d_in[8];
  const int* seg_s = (const int*)d_in[9];
  const int* seg_e = (const int*)d_in[10];

  const size_t NX = (size_t)MROWS * CDIM;  // 4,816,896
  const size_t NW = (size_t)CDIM * CDIM;   // 589,824
  const size_t need = (NX * 5 + NW * 4) * 2;
  if (ws_size < need) return;

  unsigned short* xb    = (unsigned short*)d_ws;
  unsigned short* wqkb  = xb + NX;          // [1536][768] (Wq rows, then Wk rows)
  unsigned short* wvb   = wqkb + 2 * NW;
  unsigned short* wpb   = wvb + NW;
  unsigned short* qkbuf = wpb + NW;         // [6272][1536]
  unsigned short* vtbuf = qkbuf + 2 * NX;   // [768][6272] — MUST follow qkbuf
  unsigned short* ybuf  = vtbuf + NX;       // MUST follow vtbuf (masked OOB reads land here)
  // split workspace: xb+wqkb region (dead after gemm_pre; cvt5 rewrites each call).
  // 672 slots x 16896 B = 11.35 MB < (NX + 2*NW)*2 = 12.0 MB. wpb untouched.
  float* wsp = (float*)d_ws;

  cvt5_kernel<<<(NX4 + 4 * NW4) / 256, 256, 0, stream>>>(x, Wq, Wk, Wv, Wp,
                                                         xb, wqkb, wvb, wpb);

  gemm_pre<<<882, 256, 0, stream>>>(xb, wqkb, wvb, bq, bk, bv, qkbuf, vtbuf);

  attn_kernel<<<dim3(48, 32), 512, 0, stream>>>(qkbuf, vtbuf, ybuf, wsp, seg_s, seg_e);
  merge2<<<336, 256, 0, stream>>>(wsp, ybuf);

  gemm_post<<<294, 256, 0, stream>>>(ybuf, wpb, bp, (float*)d_out);
}

// Round 19
// 111.634 us; speedup vs baseline: 1.0664x; 1.0664x over previous
//
#include <hip/hip_runtime.h>
#include <hip/hip_bf16.h>
#include <stdint.h>

typedef short bf16x8 __attribute__((ext_vector_type(8)));
typedef float f32x4 __attribute__((ext_vector_type(4)));

#define T_M   512
#define ML_   1536
#define LSEQ  1568
#define NHEAD 12
#define DHEAD 64
#define CDIM  768
#define NSEG  8
#define MROWS 6272  // B*L
#define CQK   1536  // q|k concat row stride
#define VTN   6272  // vt row length
#define NX4   1204224  // MROWS*CDIM/4
#define NW4   147456   // CDIM*CDIM/4
#define NWE   589824   // CDIM*CDIM
#define SCALE2 0.1803368801111244f  // 0.125 * log2(e)

__device__ __forceinline__ unsigned short f2bf(float f) {
  __hip_bfloat16 h = __float2bfloat16(f);
  return *reinterpret_cast<unsigned short*>(&h);
}

__device__ __forceinline__ void gll16(const void* g, void* l) {
  auto* lp = reinterpret_cast<__attribute__((address_space(3))) unsigned int*>(
      reinterpret_cast<uintptr_t>(l));
  auto* gp = reinterpret_cast<const __attribute__((address_space(1))) unsigned int*>(
      reinterpret_cast<uintptr_t>(g));
  __builtin_amdgcn_global_load_lds(gp, lp, 16, 0, 0);
}

__device__ __forceinline__ f32x4 mfma16(bf16x8 a, bf16x8 b, f32x4 c) {
  return __builtin_amdgcn_mfma_f32_16x16x32_bf16(a, b, c, 0, 0, 0);
}

// Bijective XCD-chunk remap (m204): consecutive wgids land on one XCD.
__device__ __forceinline__ int xcd_chunk(int orig, int nwg) {
  int q = nwg >> 3, r = nwg & 7;
  int xcd = orig & 7, i = orig >> 3;
  return (xcd < r ? xcd * (q + 1) : r * (q + 1) + (xcd - r) * q) + i;
}

// Single fused f32->bf16 convert for x, Wq, Wk, Wv, Wp.
__global__ __launch_bounds__(256) void cvt5_kernel(const float* __restrict__ x,
                                                   const float* __restrict__ wq,
                                                   const float* __restrict__ wk,
                                                   const float* __restrict__ wv,
                                                   const float* __restrict__ wp,
                                                   unsigned short* __restrict__ xb,
                                                   unsigned short* __restrict__ wqkb,
                                                   unsigned short* __restrict__ wvb,
                                                   unsigned short* __restrict__ wpb) {
  int gid = blockIdx.x * 256 + threadIdx.x;
  const float* src;
  unsigned short* dst;
  int idx;
  if (gid < NX4) {
    src = x; dst = xb; idx = gid;
  } else {
    int g = gid - NX4;
    int region = g / NW4;
    idx = g - region * NW4;
    if (region == 0)      { src = wq; dst = wqkb; }
    else if (region == 1) { src = wk; dst = wqkb + NWE; }
    else if (region == 2) { src = wv; dst = wvb; }
    else                  { src = wp; dst = wpb; }
  }
  float4 v = reinterpret_cast<const float4*>(src)[idx];
  __hip_bfloat162 lo = __float22bfloat162_rn({v.x, v.y});
  __hip_bfloat162 hi = __float22bfloat162_rn({v.z, v.w});
  uint2 st;
  st.x = *reinterpret_cast<unsigned*>(&lo);
  st.y = *reinterpret_cast<unsigned*>(&hi);
  reinterpret_cast<uint2*>(dst)[idx] = st;
}

// Shared GEMM body (128x128, 256 thr): C[m,n] = (sum A[m,k]*Bw[n,k] + bias)*sc.
template <int OUT_BF16, int BIAS_ROW>
__device__ __forceinline__ void gemm_body(char* smem, int bx, int by,
                                          const unsigned short* __restrict__ A,
                                          const unsigned short* __restrict__ Bw,
                                          const float* __restrict__ bias0,
                                          const float* __restrict__ bias1, int bsplit,
                                          float sc0, float sc1,
                                          void* __restrict__ Cout,
                                          int M, int N, int K) {
  const int tid = threadIdx.x;
  const int lane = tid & 63;
  const int w = tid >> 6;
  const int m0 = by * 128, n0 = bx * 128;
  const int wr = (w >> 1) * 64, wc = (w & 1) * 64;

  unsigned gaoff[4], gboff[4];
#pragma unroll
  for (int it = 0; it < 4; ++it) {
    int off = it * 4096 + tid * 16;
    int r = off >> 7;
    int cb = (off & 127) ^ ((r & 7) << 4);
    gaoff[it] = (unsigned)((m0 + r) * K * 2 + cb);
    gboff[it] = (unsigned)((n0 + r) * K * 2 + cb);
  }
  const char* Ab = (const char*)A;
  const char* Bb = (const char*)Bw;

  f32x4 acc[4][4] = {};

  for (int ks = 0; ks < K; ks += 64) {
    __syncthreads();
#pragma unroll
    for (int it = 0; it < 4; ++it) {
      gll16(Ab + gaoff[it] + ks * 2, smem + it * 4096 + tid * 16);
      gll16(Bb + gboff[it] + ks * 2, smem + 16384 + it * 4096 + tid * 16);
    }
    __syncthreads();
#pragma unroll
    for (int kk = 0; kk < 2; ++kk) {
      const int cb = kk * 64 + (lane >> 4) * 16;
      bf16x8 av[4], bv[4];
#pragma unroll
      for (int mi = 0; mi < 4; ++mi) {
        int r = wr + mi * 16 + (lane & 15);
        av[mi] = *reinterpret_cast<const bf16x8*>(smem + r * 128 + (cb ^ ((r & 7) << 4)));
      }
#pragma unroll
      for (int ni = 0; ni < 4; ++ni) {
        int r = wc + ni * 16 + (lane & 15);
        bv[ni] = *reinterpret_cast<const bf16x8*>(smem + 16384 + r * 128 + (cb ^ ((r & 7) << 4)));
      }
#pragma unroll
      for (int mi = 0; mi < 4; ++mi)
#pragma unroll
        for (int ni = 0; ni < 4; ++ni)
          acc[mi][ni] = mfma16(av[mi], bv[ni], acc[mi][ni]);
    }
  }

#pragma unroll
  for (int mi = 0; mi < 4; ++mi) {
#pragma unroll
    for (int ni = 0; ni < 4; ++ni) {
      int col = n0 + wc + ni * 16 + (lane & 15);
      float bsc = BIAS_ROW ? 0.f : (col < bsplit ? bias0[col] : bias1[col - bsplit]);
      float scc = BIAS_ROW ? 1.f : (col < bsplit ? sc0 : sc1);
#pragma unroll
      for (int reg = 0; reg < 4; ++reg) {
        int row = m0 + wr + mi * 16 + (lane >> 4) * 4 + reg;
        float v = (acc[mi][ni][reg] + (BIAS_ROW ? bias0[row] : bsc)) * scc;
        if (OUT_BF16)
          ((unsigned short*)Cout)[(size_t)row * N + col] = f2bf(v);
        else
          ((float*)Cout)[(size_t)row * N + col] = v;
      }
    }
  }
}

// Fused pre-attention GEMMs with XCD-chunked block remap:
// wgid [0,588) = Q|K proj (12x49; 12-block runs share an A-panel),
// wgid [588,882) = V^T (49x6; 49-block runs share the wv A-panel).
__global__ __launch_bounds__(256) void gemm_pre(const unsigned short* __restrict__ xb,
                                                const unsigned short* __restrict__ wqkb,
                                                const unsigned short* __restrict__ wvb,
                                                const float* __restrict__ bq,
                                                const float* __restrict__ bk,
                                                const float* __restrict__ bv,
                                                unsigned short* __restrict__ qkbuf,
                                                unsigned short* __restrict__ vtbuf) {
  __shared__ char smem[32768];
  int bid = xcd_chunk(blockIdx.x, 882);
  if (bid < 588) {
    gemm_body<1, 0>(smem, bid % 12, bid / 12, xb, wqkb, bq, bk, 768, SCALE2, 1.0f,
                    qkbuf, MROWS, CQK, CDIM);
  } else {
    int b2 = bid - 588;
    gemm_body<1, 1>(smem, b2 % 49, b2 / 49, wvb, xb, bv, bv, 0, 1.0f, 1.0f,
                    vtbuf, CDIM, MROWS, CDIM);
  }
}

// Final projection GEMM, 1-D grid + XCD-chunked remap (6-block runs share ybuf panel).
__global__ __launch_bounds__(256) void gemm_post(const unsigned short* __restrict__ ybuf,
                                                 const unsigned short* __restrict__ wpb,
                                                 const float* __restrict__ bp,
                                                 float* __restrict__ out) {
  __shared__ char smem[32768];
  int bid = xcd_chunk(blockIdx.x, 294);
  gemm_body<0, 0>(smem, bid % 6, bid / 6, ybuf, wpb, bp, bp, 1 << 30, 1.0f, 1.0f,
                  out, MROWS, CDIM, CDIM);
}

// LPT order of the 25 qt units, descending ceil(cnt/2).
__device__ const unsigned char qlpt[25] = {
    15, 23, 24, 14, 22, 13, 21, 12, 20, 11, 19, 10, 18,
    9, 17, 7, 6, 5, 4, 8, 16, 3, 2, 1, 0};

// next included KV-tile after kt for this qt
__device__ __forceinline__ int step_kt(int kt, int rb, int qtl) {
  if (rb == 0 || rb == 3) return kt + 1;
  if ((kt & 7) < qtl) return kt + 1;
  if (kt < 16) return (kt & ~7) + 8;
  return 24;
}

// Flash attention (R9 structure, proven 53.0us) + clamp-free affine staging
// (OOB K-rows land in vtbuf, all masked positions) + kt==24 half-tile skip
// (text cols 32..63 are always masked -> skip half the MFMAs/exp there).
// Grid: (48 bh, 25 qt-rank), 512 threads.
__global__ __launch_bounds__(512) void attn_kernel(const unsigned short* __restrict__ qk,
                                                   const unsigned short* __restrict__ vt,
                                                   unsigned short* __restrict__ yb,
                                                   const int* __restrict__ seg_s,
                                                   const int* __restrict__ seg_e) {
  __shared__ char smem[49664];  // [2 tiles][K 8KB|V 8KB] + P[8][2KB] + m/l 512B
  const int tid = threadIdx.x;
  const int lane = tid & 63;
  const int w = tid >> 6;
  const int lh = lane & 15, lg = lane >> 4;
  const int bh = blockIdx.x;
  const int b = bh / NHEAD, h = bh % NHEAD;
  const int qt = qlpt[blockIdx.y];
  const int wsub = w & 3;
  const int half = w >> 2;
  const int rb_q = qt >> 3;   // 0,1,2 motion; 3 text
  const int qtl = qt & 7;
  const int cnt = (rb_q == 0) ? (qtl + 1) : (rb_q < 3 ? 3 * (qtl + 1) + 1 : 25);
  char* pw = smem + 32768 + w * 2048;

  // Q fragments (pre-scaled into log2 domain); MFMA B-operand.
  int qr = qt * 64 + wsub * 16 + lh;
  if (qr >= LSEQ) qr = LSEQ - 1;
  const unsigned short* qp = qk + ((size_t)(b * LSEQ + qr) * CQK + h * DHEAD + lg * 8);
  const bf16x8 qf0 = *reinterpret_cast<const bf16x8*>(qp);
  const bf16x8 qf1 = *reinterpret_cast<const bf16x8*>(qp + 32);

  const char* qkc = (const char*)qk + (size_t)b * LSEQ * CQK * 2;
  const char* vtc = (const char*)vt + (size_t)b * LSEQ * 2;

  // staging precompute (waves 0-3: K rows, waves 4-7: V rows; both pair tiles).
  // Addresses are AFFINE in kt (no clamp): worst OOB K read is 31 rows past
  // qkbuf which lands in vtbuf (contiguous) and only feeds always-masked
  // positions (text cols 32..63), so garbage is harmless.
  const int cbyte = (((lane & 7) ^ (lane >> 3)) << 4);
  const int rlA = (w & 3) * 16 + (lane >> 3);
  const char* kqbase = qkc + (768 + h * DHEAD) * 2 + cbyte;
  const char* kAbase[2];
#pragma unroll
  for (int t = 0; t < 2; ++t)
    kAbase[t] = kqbase + (size_t)(rlA + t * 8) * (CQK * 2);
  const char* vAbase[2];
#pragma unroll
  for (int t = 0; t < 2; ++t)
    vAbase[t] = vtc + (size_t)(h * DHEAD + rlA + t * 8) * (VTN * 2) + cbyte;

  const int c0 = (lg * 16) ^ ((lh & 7) << 4);

  // loop-invariant mask data (swapped layout: lane q = lh; k = nt*16+lg*4+reg)
  const int f_lane = (qt * 64 + wsub * 16 + lh) & 511;
  float a_k[4];
#pragma unroll
  for (int nt = 0; nt < 4; ++nt) {
    int j = nt * 2 + (lg >> 1);
    bool st = (rb_q == 3) || ((rb_q == 1) ? (j != 1) : (j != 0));
    a_k[nt] = (nt < 2 && st) ? 0.f : -1e30f;
  }
  float w4[4];
#pragma unroll
  for (int reg = 0; reg < 4; ++reg) {
    int ii = (lg * 4 + reg) & 7;
    int ssv = seg_s[b * NSEG + ii], sev = seg_e[b * NSEG + ii];
    w4[reg] = (rb_q == 3) ? 0.f : ((f_lane >= ssv && f_lane < sev) ? 0.f : -1e30f);
  }

  // P LDS addresses
  int pfa[2];
#pragma unroll
  for (int jc = 0; jc < 2; ++jc)
    pfa[jc] = lh * 128 + (((jc * 32 + lg * 8) * 2) ^ ((lh & 7) << 4));
  int pwr[4];
#pragma unroll
  for (int nt = 0; nt < 4; ++nt)
    pwr[nt] = lh * 128 + ((nt * 32 + lg * 8) ^ ((lh & 7) << 4));

  const short oneb = (short)0x3F80;
  const bf16x8 ones = {oneb, oneb, oneb, oneb, oneb, oneb, oneb, oneb};

  f32x4 o[4] = {};
  f32x4 l_acc = {};
  float m_run = -1e30f;  // per-lane (q = lh), log2 domain

  int ktA = 0;
  int ktB = step_kt(0, rb_q, qtl);
  if (ktB > 24) ktB = 24;
  const int niter = (cnt + 1) >> 1;

  for (int j = 0; j < niter; ++j) {
    __syncthreads();  // previous pair fully consumed

    // stage both halves' tiles (single-buffered, affine addresses)
    int kts0 = ktA, kts1 = ktB;
#pragma unroll
    for (int q = 0; q < 2; ++q) {
      int kt = q ? kts1 : kts0;
#pragma unroll
      for (int t = 0; t < 2; ++t) {
        char* dst = smem + q * 16384 + (w < 4 ? 0 : 8192) + (2 * (w & 3) + t) * 1024 +
                    lane * 16;
        const char* src = (w < 4) ? (kAbase[t] + (size_t)kt * (64 * CQK * 2))
                                  : (vAbase[t] + (size_t)kt * 128);
        gll16(src, dst);
      }
    }
    __syncthreads();  // staged (compiler drains vmcnt)

    const int myidx = 2 * j + half;
    if (myidx < cnt) {
      const int kt = half ? ktB : ktA;
      const bool kt24 = (kt == 24);  // wave-uniform
      const char* kb = smem + half * 16384;
      const char* vb = kb + 8192;

      // S^T = K Q^T : s[nt][reg] = S[q=lh][k = nt*16 + lg*4 + reg]
      // kt==24: k >= 32 (nt 2,3) is always masked -> skip those MFMAs.
      f32x4 s[4];
#pragma unroll
      for (int nt = 0; nt < 4; ++nt) {
        if (nt >= 2 && kt24) {
          s[nt][0] = s[nt][1] = s[nt][2] = s[nt][3] = -1e30f;
        } else {
          const char* kr = kb + (nt * 16 + lh) * 128;
          bf16x8 k0 = *reinterpret_cast<const bf16x8*>(kr + c0);
          bf16x8 k1 = *reinterpret_cast<const bf16x8*>(kr + (c0 ^ 64));
          f32x4 z = {};
          z = mfma16(k0, qf0, z);
          z = mfma16(k1, qf1, z);
          s[nt] = z;
        }
      }

      // mask
      if (kt24) {
#pragma unroll
        for (int nt = 0; nt < 2; ++nt)
#pragma unroll
          for (int reg = 0; reg < 4; ++reg)
            s[nt][reg] += a_k[nt] + w4[reg];
      } else if (rb_q < 3 && (kt & 7) == qtl) {
        const int cbk = kt >> 3;
        const bool strict = (rb_q == 1) ? (cbk != 0) : ((rb_q == 2) ? (cbk == 2) : false);
        const int dbase = qtl * 64 + lg * 4;
#pragma unroll
        for (int nt = 0; nt < 4; ++nt)
#pragma unroll
          for (int reg = 0; reg < 4; ++reg) {
            int kcol = dbase + nt * 16 + reg;
            bool ok = strict ? (kcol < f_lane) : (kcol <= f_lane);
            s[nt][reg] = ok ? s[nt][reg] : -1e30f;
          }
      }

      // lane-local row max + 2 cross-lg shfl steps
      float mt = s[0][0];
#pragma unroll
      for (int nt = 0; nt < 4; ++nt)
#pragma unroll
        for (int reg = 0; reg < 4; ++reg)
          if (nt || reg) mt = fmaxf(mt, s[nt][reg]);
      mt = fmaxf(mt, __shfl_xor(mt, 16));
      mt = fmaxf(mt, __shfl_xor(mt, 32));

      if (!__all(mt <= -1e29f)) {
        if (!__all(mt <= m_run + 12.f)) {
          float mold = m_run;
          m_run = fmaxf(m_run, mt);
          float fc = exp2f(mold - m_run);
          float fcC[4];
#pragma unroll
          for (int reg = 0; reg < 4; ++reg) fcC[reg] = __shfl(fc, lg * 4 + reg);
#pragma unroll
          for (int reg = 0; reg < 4; ++reg) {
            l_acc[reg] *= fcC[reg];
#pragma unroll
            for (int dt = 0; dt < 4; ++dt) o[dt][reg] *= fcC[reg];
          }
        }

        // exp + packed P write (4 x ds_write_b64); kt==24 upper half is zero
#pragma unroll
        for (int nt = 0; nt < 4; ++nt) {
          uint2 pk;
          if (nt >= 2 && kt24) {
            pk.x = 0u; pk.y = 0u;
          } else {
            float p0 = exp2f(s[nt][0] - m_run);
            float p1 = exp2f(s[nt][1] - m_run);
            float p2 = exp2f(s[nt][2] - m_run);
            float p3 = exp2f(s[nt][3] - m_run);
            __hip_bfloat162 lo = __float22bfloat162_rn({p0, p1});
            __hip_bfloat162 hi = __float22bfloat162_rn({p2, p3});
            pk.x = *reinterpret_cast<unsigned*>(&lo);
            pk.y = *reinterpret_cast<unsigned*>(&hi);
          }
          *reinterpret_cast<uint2*>(pw + pwr[nt]) = pk;
        }

        // O += P @ V ; l += P @ 1   (kt==24: jc=1 spans k 32..63, all-zero P)
#pragma unroll
        for (int jc = 0; jc < 2; ++jc) {
          if (jc == 0 || !kt24) {
            bf16x8 pf = *reinterpret_cast<const bf16x8*>(pw + pfa[jc]);
#pragma unroll
            for (int dt = 0; dt < 4; ++dt) {
              bf16x8 vf = *reinterpret_cast<const bf16x8*>(
                  vb + (dt * 16 + lh) * 128 + (c0 ^ (jc << 6)));
              o[dt] = mfma16(pf, vf, o[dt]);
            }
            l_acc = mfma16(pf, ones, l_acc);
          }
        }
      }
    }

    // advance both halves' tiles by 2 positions
    ktA = step_kt(ktB, rb_q, qtl);
    if (ktA > 24) ktA = 24;
    ktB = step_kt(ktA, rb_q, qtl);
    if (ktB > 24) ktB = 24;
  }

  // ---- merge the two KV-halves (reuse staging LDS) ----
  float* olds = (float*)smem;                 // [4][16][64] f32 = 16KB
  float* mf = (float*)(smem + 16384);         // [4][16]
  float* lf = (float*)(smem + 16384 + 256);   // [4][16]
  __syncthreads();
  if (half == 0) {
#pragma unroll
    for (int reg = 0; reg < 4; ++reg) {
#pragma unroll
      for (int dt = 0; dt < 4; ++dt)
        olds[(wsub * 16 + lg * 4 + reg) * 64 + dt * 16 + lh] = o[dt][reg];
      if (lh == 0) lf[wsub * 16 + lg * 4 + reg] = l_acc[reg];
    }
    if (lg == 0) mf[wsub * 16 + lh] = m_run;
  }
  __syncthreads();
  if (half == 1) {
#pragma unroll
    for (int reg = 0; reg < 4; ++reg) {
      int row = lg * 4 + reg;
      int r = qt * 64 + wsub * 16 + row;
      if (r >= LSEQ) continue;
      float m1 = mf[wsub * 16 + row];
      float l1 = lf[wsub * 16 + row];
      float m2 = __shfl(m_run, row);
      float M = fmaxf(m1, m2);
      float w1 = exp2f(m1 - M);
      float w2 = exp2f(m2 - M);
      float inv = 1.0f / (l1 * w1 + l_acc[reg] * w2);
#pragma unroll
      for (int dt = 0; dt < 4; ++dt) {
        int col = dt * 16 + lh;
        float v = (olds[(wsub * 16 + row) * 64 + col] * w1 + o[dt][reg] * w2) * inv;
        yb[(size_t)(b * LSEQ + r) * CDIM + h * DHEAD + col] = f2bf(v);
      }
    }
  }
}

extern "C" void kernel_launch(void* const* d_in, const int* in_sizes, int n_in,
                              void* d_out, int out_size, void* d_ws, size_t ws_size,
                              hipStream_t stream) {
  (void)in_sizes; (void)n_in; (void)out_size;
  const float* x  = (const float*)d_in[0];
  const float* Wq = (const float*)d_in[1];
  const float* bq = (const float*)d_in[2];
  const float* Wk = (const float*)d_in[3];
  const float* bk = (const float*)d_in[4];
  const float* Wv = (const float*)d_in[5];
  const float* bv = (const float*)d_in[6];
  const float* Wp = (const float*)d_in[7];
  const float* bp = (const float*)d_in[8];
  const int* seg_s = (const int*)d_in[9];
  const int* seg_e = (const int*)d_in[10];

  const size_t NX = (size_t)MROWS * CDIM;  // 4,816,896
  const size_t NW = (size_t)CDIM * CDIM;   // 589,824
  const size_t need = (NX * 5 + NW * 4) * 2;
  if (ws_size < need) return;

  unsigned short* xb    = (unsigned short*)d_ws;
  unsigned short* wqkb  = xb + NX;          // [1536][768] (Wq rows, then Wk rows)
  unsigned short* wvb   = wqkb + 2 * NW;
  unsigned short* wpb   = wvb + NW;
  unsigned short* qkbuf = wpb + NW;         // [6272][1536]
  unsigned short* vtbuf = qkbuf + 2 * NX;   // [768][6272] — MUST follow qkbuf
  unsigned short* ybuf  = vtbuf + NX;       // MUST follow vtbuf (masked OOB reads land here)

  cvt5_kernel<<<(NX4 + 4 * NW4) / 256, 256, 0, stream>>>(x, Wq, Wk, Wv, Wp,
                                                         xb, wqkb, wvb, wpb);

  gemm_pre<<<882, 256, 0, stream>>>(xb, wqkb, wvb, bq, bk, bv, qkbuf, vtbuf);

  attn_kernel<<<dim3(48, 25), 512, 0, stream>>>(qkbuf, vtbuf, ybuf, seg_s, seg_e);

  gemm_post<<<294, 256, 0, stream>>>(ybuf, wpb, bp, (float*)d_out);
}